// Round 10
// baseline (319.107 us; speedup 1.0000x reference)
//
#include <hip/hip_runtime.h>
#include <hip/hip_bf16.h>

#define NN 10000
#define NE 100000

typedef __attribute__((ext_vector_type(8))) short short8v;
typedef __attribute__((ext_vector_type(4))) short short4v;
typedef __attribute__((ext_vector_type(4))) float float4v;

__device__ __forceinline__ int bcast_i(int v, int k) {  // k must be unrolled-constant
  return __builtin_amdgcn_readlane(v, k);
}
__device__ __forceinline__ unsigned int enc_f(float f) {
  unsigned int u = __float_as_uint(f);
  return (u & 0x80000000u) ? ~u : (u | 0x80000000u);
}
__device__ __forceinline__ float dec_f(unsigned int u) {
  return __uint_as_float((u & 0x80000000u) ? (u & 0x7fffffffu) : ~u);
}
__device__ __forceinline__ float silu_f(float x) {
  return x / (1.0f + __expf(-x));
}
__device__ __forceinline__ float b2f(short s) {
  return __uint_as_float(((unsigned int)(unsigned short)s) << 16);
}
// fp32 -> bf16 hi/lo split: x ~= hi + lo with ~2^-16 relative error.
__device__ __forceinline__ void f32_hilo(float x, short& h, short& l) {
  __hip_bfloat16 bh = __float2bfloat16(x);
  float r = x - __bfloat162float(bh);
  __hip_bfloat16 bl = __float2bfloat16(r);
  h = __builtin_bit_cast(short, bh);
  l = __builtin_bit_cast(short, bl);
}
__device__ __forceinline__ short f2bf(float x) {
  return __builtin_bit_cast(short, __float2bfloat16(x));
}
#define MFMA16(a, b, c) __builtin_amdgcn_mfma_f32_16x16x32_bf16(a, b, c, 0, 0, 0)

// issue the 18 nb row loads for one edge (e = unrolled constant -> readlane legal)
__device__ __forceinline__ void g_issue(const float* __restrict__ nb, int idx_v,
                                        int e, int lane,
                                        float (&VS)[9], float (&VT)[9]) {
  int se_ = bcast_i(idx_v, e);
  int de_ = bcast_i(idx_v, 16 + e);
  const float* __restrict__ ps_ = nb + (size_t)se_ * 576 + lane;
  const float* __restrict__ pt_ = nb + (size_t)de_ * 576 + lane;
#pragma unroll
  for (int j = 0; j < 9; ++j) {
    VS[j] = ps_[j * 64];
    VT[j] = pt_[j * 64];
  }
}

// ---------------- prep: Q + MFMA weight fragment packs (unchanged).
__global__ void prep_kernel(const float* __restrict__ W_msg, const float* __restrict__ W_val,
                            const float* __restrict__ W_out, const float* __restrict__ W_rbf,
                            const float* __restrict__ W_gate,
                            float* __restrict__ Q,
                            short* __restrict__ Wp1h, short* __restrict__ Wp1l,
                            short* __restrict__ Wp2h, short* __restrict__ Wp2l,
                            short* __restrict__ Wp3h, short* __restrict__ Wp3l,
                            short* __restrict__ Wp4h, short* __restrict__ Wp4l) {
  int i = blockIdx.x * blockDim.x + threadIdx.x;  // grid = 192*256 = 49152
  if (i < 1024) {
    int c = i >> 3, h = i & 7;
    float s = 0.0f;
#pragma unroll
    for (int dv = 0; dv < 16; ++dv)
      s += W_val[c * 128 + h * 16 + dv] * W_out[h * 16 + dv];
    Q[c * 8 + h] = s;
  }
  const float* W; short* ph; short* pl; int KF, Nw, local; bool tr = false;
  if (i < 8192)       { W = W_rbf;  ph = Wp1h; pl = Wp1l; KF = 4; Nw = 64;  local = i; }
  else if (i < 16384) { W = W_gate; ph = Wp2h; pl = Wp2l; KF = 2; Nw = 128; local = i - 8192; }
  else if (i < 32768) { W = W_msg;  ph = Wp3h; pl = Wp3l; KF = 4; Nw = 128; local = i - 16384; }
  else                { W = W_msg;  ph = Wp4h; pl = Wp4l; KF = 4; Nw = 128; local = i - 32768; tr = true; }
  int tile = local >> 9;           // nt*KF + kf
  int ln = (local >> 3) & 63;
  int j = local & 7;
  int nt = tile / KF, kf = tile % KF;
  int k = kf * 32 + 8 * (ln >> 4) + j;
  int n = nt * 16 + (ln & 15);
  float w = tr ? W[n * 128 + k] : W[k * Nw + n];
  short h, lo;
  f32_hilo(w, h, lo);
  ph[local] = h;
  pl[local] = lo;
}

// ---------------- pass1 (FUSED, r5 structure + Gb fold): gather (with full
// 9-row wig transform -> Gb), then GEMM1/2/3 -> gate, logits, segment-max.
// Per-wave LDS only, no barriers; 2-deep gather pipeline.
__global__ __launch_bounds__(256, 3) void pass1_kernel(
    const float* __restrict__ nb, const int* __restrict__ zn,
    const float* __restrict__ dist, const int* __restrict__ ei,
    const float* __restrict__ wig, const float* __restrict__ aemb,
    const float* __restrict__ alpha,
    const short* __restrict__ Wp1h, const short* __restrict__ Wp1l,
    const short* __restrict__ Wp2h, const short* __restrict__ Wp2l,
    const short* __restrict__ Wp3h, const short* __restrict__ Wp3l,
    float* __restrict__ logits, unsigned int* __restrict__ m_enc,
    __hip_bfloat16* __restrict__ gate_ws, short* __restrict__ Gb) {
  __shared__ __attribute__((aligned(16))) float xe_s[4][16][132];
  const int tid = threadIdx.x;
  const int lane = tid & 63;
  const int wid = tid >> 6;
  const int g = lane >> 4;
  const int col = lane & 15;
  const int e0 = (blockIdx.x * 4 + wid) * 16;

  // wave's 32 edge indices: lanes 0..15 = src, 16..31 = dst
  int l16 = lane & 15;
  int ecl16 = (e0 + l16 < NE) ? e0 + l16 : NE - 1;
  int idx_v = 0;
  if (lane < 32) idx_v = ei[(lane < 16 ? 0 : NE) + ecl16];

  int ecol = e0 + col; if (ecol >= NE) ecol = NE - 1;
  const float d = dist[ecol];

  // consume one edge: full 9-row wig transform; row0 -> xe_s; G -> Gb.
  auto consume = [&](int e, const float (&vs)[9], const float (&vt)[9]) {
    int eu = e0 + e;
    int ec = eu < NE ? eu : NE - 1;
    const float* __restrict__ pw = wig + (size_t)ec * 81;  // wave-uniform
    float Gs0 = 0, Gs1 = 0, Gs2 = 0, Gt0 = 0, Gt1 = 0, Gt2 = 0;
#pragma unroll
    for (int j = 0; j < 9; ++j) {
      float rr[9];
#pragma unroll
      for (int jp = 0; jp < 9; ++jp) rr[jp] = pw[j * 9 + jp];
      float xs = 0.0f, xt = 0.0f;
#pragma unroll
      for (int jp = 0; jp < 9; ++jp) { xs += rr[jp] * vs[jp]; xt += rr[jp] * vt[jp]; }
      if (j == 0) {
        xe_s[wid][e][lane] = xs;
        xe_s[wid][e][64 + lane] = xt;
      }
      Gs0 += rr[1] * xs; Gs1 += rr[2] * xs; Gs2 += rr[3] * xs;
      Gt0 += rr[1] * xt; Gt1 += rr[2] * xt; Gt2 += rr[3] * xt;
    }
    if (eu < NE) {
      short* gp = Gb + (size_t)ec * 384 + lane;
      gp[0]   = f2bf(Gs0);
      gp[64]  = f2bf(Gs1);
      gp[128] = f2bf(Gs2);
      gp[192] = f2bf(Gt0);
      gp[256] = f2bf(Gt1);
      gp[320] = f2bf(Gt2);
    }
  };

  // ---- gather, 2-deep pipelined ----
  float vs0[9], vt0[9], vs1[9], vt1[9];
  g_issue(nb, idx_v, 0, lane, vs0, vt0);
  g_issue(nb, idx_v, 1, lane, vs1, vt1);
#pragma unroll
  for (int e = 0; e < 16; e += 2) {
    consume(e, vs0, vt0);
    if (e + 2 < 16) g_issue(nb, idx_v, e + 2, lane, vs0, vt0);
    consume(e + 1, vs1, vt1);
    if (e + 3 < 16) g_issue(nb, idx_v, e + 3, lane, vs1, vt1);
  }

  // ---- rbf A-frags (direct in fragment layout) ----
  short8v a1h[4], a1l[4];
#pragma unroll
  for (int kf = 0; kf < 4; ++kf) {
#pragma unroll
    for (int j = 0; j < 8; ++j) {
      int k = kf * 32 + 8 * g + j;
      float t = d - (float)k * (1.0f / 127.0f);
      float v = __expf(-8192.0f * t * t);
      short h, lo; f32_hilo(v, h, lo);
      a1h[kf][j] = h; a1l[kf][j] = lo;
    }
  }

  // ---- A3 frags from xe_s BEFORE es overwrites the buffer ----
  short8v a3h[4], a3l[4];
#pragma unroll
  for (int kf = 0; kf < 4; ++kf) {
    const float* p = &xe_s[wid][col][kf * 32 + 8 * g];
    float4v v0 = *(const float4v*)p;
    float4v v1 = *(const float4v*)(p + 4);
#pragma unroll
    for (int j = 0; j < 4; ++j) {
      short h, lo;
      f32_hilo(v0[j], h, lo); a3h[kf][j] = h;     a3l[kf][j] = lo;
      f32_hilo(v1[j], h, lo); a3h[kf][4 + j] = h; a3l[kf][4 + j] = lo;
    }
  }

  const float4v z4 = {0.0f, 0.0f, 0.0f, 0.0f};

  // ---- GEMM1: es_raw(16x64) = rbf(16x128) @ W_rbf ----
  float4v acc1[4];
#pragma unroll
  for (int nt = 0; nt < 4; ++nt) {
    float4v a = z4;
#pragma unroll
    for (int kf = 0; kf < 4; ++kf) {
      short8v bh = *(const short8v*)(Wp1h + ((nt * 4 + kf) * 64 + lane) * 8);
      short8v bl = *(const short8v*)(Wp1l + ((nt * 4 + kf) * 64 + lane) * 8);
      a = MFMA16(a1h[kf], bh, a);
      a = MFMA16(a1h[kf], bl, a);
      a = MFMA16(a1l[kf], bh, a);
    }
    acc1[nt] = a;
  }

  // ---- bias + silu -> es rows (reuse xe_s; per-wave in-order LDS) ----
  int dn_r[4];
#pragma unroll
  for (int r = 0; r < 4; ++r) {
    int sn = __shfl(idx_v, 4 * g + r);
    dn_r[r] = __shfl(idx_v, 16 + 4 * g + r);
    int zs = zn[sn], zd = zn[dn_r[r]];
#pragma unroll
    for (int nt = 0; nt < 4; ++nt) {
      float b = aemb[zs * 64 + nt * 16 + col] + aemb[zd * 64 + nt * 16 + col];
      xe_s[wid][4 * g + r][nt * 16 + col] = silu_f(acc1[nt][r] + b);
    }
  }

  // ---- GEMM2 A-frags from es rows ----
  short8v a2h[2], a2l[2];
#pragma unroll
  for (int kf = 0; kf < 2; ++kf) {
    const float* p = &xe_s[wid][col][kf * 32 + 8 * g];
    float4v v0 = *(const float4v*)p;
    float4v v1 = *(const float4v*)(p + 4);
#pragma unroll
    for (int j = 0; j < 4; ++j) {
      short h, lo;
      f32_hilo(v0[j], h, lo); a2h[kf][j] = h;     a2l[kf][j] = lo;
      f32_hilo(v1[j], h, lo); a2h[kf][4 + j] = h; a2l[kf][4 + j] = lo;
    }
  }

  // ---- GEMM2: gate = silu(es @ W_gate), store bf16 ----
  float gate_r[8][4];
#pragma unroll
  for (int nt = 0; nt < 8; ++nt) {
    float4v a = z4;
#pragma unroll
    for (int kf = 0; kf < 2; ++kf) {
      short8v bh = *(const short8v*)(Wp2h + ((nt * 2 + kf) * 64 + lane) * 8);
      short8v bl = *(const short8v*)(Wp2l + ((nt * 2 + kf) * 64 + lane) * 8);
      a = MFMA16(a2h[kf], bh, a);
      a = MFMA16(a2h[kf], bl, a);
      a = MFMA16(a2l[kf], bh, a);
    }
#pragma unroll
    for (int r = 0; r < 4; ++r) {
      float gv = silu_f(a[r]);
      gate_r[nt][r] = gv;
      int er = e0 + 4 * g + r;
      if (er < NE)
        gate_ws[(size_t)er * 128 + nt * 16 + col] = __float2bfloat16(gv);
    }
  }

  // ---- GEMM3: msg0 = xcat @ W_msg ; epilogue: logits + segment-max ----
#pragma unroll
  for (int nt = 0; nt < 8; ++nt) {
    float4v a = z4;
#pragma unroll
    for (int kf = 0; kf < 4; ++kf) {
      short8v bh = *(const short8v*)(Wp3h + ((nt * 4 + kf) * 64 + lane) * 8);
      short8v bl = *(const short8v*)(Wp3l + ((nt * 4 + kf) * 64 + lane) * 8);
      a = MFMA16(a3h[kf], bh, a);
      a = MFMA16(a3h[kf], bl, a);
      a = MFMA16(a3l[kf], bh, a);
    }
    float al = alpha[nt * 16 + col];
#pragma unroll
    for (int r = 0; r < 4; ++r) {
      float v = a[r] * gate_r[nt][r];
      v = v > 0.0f ? v : 0.2f * v;
      v *= al;
#pragma unroll
      for (int off = 1; off < 16; off <<= 1) v += __shfl_xor(v, off);
      int er = e0 + 4 * g + r;
      if (col == 0 && er < NE) {
        logits[(size_t)er * 8 + nt] = v;
        atomicMax(&m_enc[dn_r[r] * 8 + nt], enc_f(v));
      }
    }
  }
}

// ---------------- pass2: den[n,h] += exp(logit - m[n,h])  [unchanged]
__global__ void pass2_kernel(const float* __restrict__ logits,
                             const int* __restrict__ ei,
                             const unsigned int* __restrict__ m_enc,
                             float* __restrict__ den) {
  int i = blockIdx.x * blockDim.x + threadIdx.x;
  if (i >= NE * 8) return;
  int e = i >> 3, h = i & 7;
  int dn = ei[NE + e];
  float mm = dec_f(m_enc[dn * 8 + h]);
  atomicAdd(&den[dn * 8 + h], __expf(logits[i] - mm));
}

// ---------------- pass3 (fused, M=16): attn -> u -> t (MFMA) -> forces.
// Force phase reads only the streaming Gb: zero random access. [unchanged]
__global__ __launch_bounds__(256, 3) void pass3_kernel(
    const int* __restrict__ ei, const float* __restrict__ logits,
    const unsigned int* __restrict__ m_enc, const float* __restrict__ den,
    const __hip_bfloat16* __restrict__ gate_ws, const float* __restrict__ Q,
    const short* __restrict__ Wp4h, const short* __restrict__ Wp4l,
    const short* __restrict__ Gb, float* __restrict__ out) {
  __shared__ __attribute__((aligned(16))) float attn_s[4][16][8];
  __shared__ __attribute__((aligned(16))) float x_s[4][16][132];  // u, then t
  const int tid = threadIdx.x;
  const int lane = tid & 63;
  const int wid = tid >> 6;
  const int g = lane >> 4;
  const int col = lane & 15;
  const int e0 = (blockIdx.x * 4 + wid) * 16;

  // ---- phase A: attn for 16 edges x 8 heads ----
#pragma unroll
  for (int half = 0; half < 2; ++half) {
    int i = half * 64 + lane;
    int e = i >> 3, h = i & 7;
    int ec = e0 + e; if (ec >= NE) ec = NE - 1;
    int dn = ei[NE + ec];
    float l = logits[(size_t)ec * 8 + h];
    float mm = dec_f(m_enc[dn * 8 + h]);
    float dv = den[dn * 8 + h];
    attn_s[wid][e][h] = __expf(l - mm) / (dv + 1e-9f);
  }

  // ---- phase B: u[e, m] for m = 2*lane, 2*lane+1 (paired bf16 gate load) ----
  float q0[8], q1[8];
#pragma unroll
  for (int h = 0; h < 8; ++h) {
    q0[h] = Q[(2 * lane) * 8 + h];
    q1[h] = Q[(2 * lane + 1) * 8 + h];
  }
#pragma unroll 4
  for (int e = 0; e < 16; ++e) {
    int ec = e0 + e; if (ec >= NE) ec = NE - 1;
    float4v a0 = *(const float4v*)&attn_s[wid][e][0];
    float4v a1 = *(const float4v*)&attn_s[wid][e][4];
    float wv0 = 0.0f, wv1 = 0.0f;
#pragma unroll
    for (int h = 0; h < 4; ++h) {
      wv0 += q0[h] * a0[h] + q0[4 + h] * a1[h];
      wv1 += q1[h] * a0[h] + q1[4 + h] * a1[h];
    }
    unsigned int gp = *(const unsigned int*)(gate_ws + (size_t)ec * 128 + 2 * lane);
    float gg0 = __uint_as_float((gp & 0xffffu) << 16);
    float gg1 = __uint_as_float((gp & 0xffff0000u));
    float2 uu; uu.x = gg0 * wv0; uu.y = gg1 * wv1;
    *(float2*)&x_s[wid][e][2 * lane] = uu;
  }

  // ---- phase C: A-frags from u, T = U @ Wp4 (96 MFMA), t -> x_s ----
  short8v ah[4], al[4];
#pragma unroll
  for (int kf = 0; kf < 4; ++kf) {
    const float* p = &x_s[wid][col][kf * 32 + 8 * g];
    float4v v0 = *(const float4v*)p;
    float4v v1 = *(const float4v*)(p + 4);
#pragma unroll
    for (int j = 0; j < 4; ++j) {
      short h, lo;
      f32_hilo(v0[j], h, lo); ah[kf][j] = h;     al[kf][j] = lo;
      f32_hilo(v1[j], h, lo); ah[kf][4 + j] = h; al[kf][4 + j] = lo;
    }
  }
  const float4v z4 = {0.0f, 0.0f, 0.0f, 0.0f};
#pragma unroll
  for (int nt = 0; nt < 8; ++nt) {
    float4v a = z4;
#pragma unroll
    for (int kf = 0; kf < 4; ++kf) {
      short8v bh = *(const short8v*)(Wp4h + ((nt * 4 + kf) * 64 + lane) * 8);
      short8v bl = *(const short8v*)(Wp4l + ((nt * 4 + kf) * 64 + lane) * 8);
      a = MFMA16(ah[kf], bh, a);
      a = MFMA16(ah[kf], bl, a);
      a = MFMA16(al[kf], bh, a);
    }
#pragma unroll
    for (int r = 0; r < 4; ++r)
      x_s[wid][4 * g + r][nt * 16 + col] = a[r];
  }

  // ---- phase D: forces from Gb (streaming) ; 4 edges parallel, 16 lanes each ----
  const int cg = col * 4;  // 4 channels per lane
#pragma unroll
  for (int it = 0; it < 4; ++it) {
    int e = it * 4 + g;
    int eu = e0 + e;
    bool valid = eu < NE;
    int ec = valid ? eu : NE - 1;
    int de = ei[NE + ec];
    float4v t0 = *(const float4v*)&x_s[wid][e][cg];
    float4v t1 = *(const float4v*)&x_s[wid][e][64 + cg];
    const short* gp = Gb + (size_t)ec * 384 + cg;
    float p[3];
#pragma unroll
    for (int i = 0; i < 3; ++i) {
      short4v gs = *(const short4v*)(gp + i * 64);
      short4v gt = *(const short4v*)(gp + (3 + i) * 64);
      p[i] = b2f(gs[0]) * t0[0] + b2f(gs[1]) * t0[1] + b2f(gs[2]) * t0[2] + b2f(gs[3]) * t0[3] +
             b2f(gt[0]) * t1[0] + b2f(gt[1]) * t1[1] + b2f(gt[2]) * t1[2] + b2f(gt[3]) * t1[3];
    }
#pragma unroll
    for (int i = 0; i < 3; ++i)
#pragma unroll
      for (int off = 1; off < 16; off <<= 1) p[i] += __shfl_xor(p[i], off);
    float pv = (col == 1) ? p[0] : ((col == 2) ? p[1] : p[2]);
    if (valid && col >= 1 && col <= 3)
      atomicAdd(&out[de * 3 + (col - 1)], pv);
  }
}

extern "C" void kernel_launch(void* const* d_in, const int* in_sizes, int n_in,
                              void* d_out, int out_size, void* d_ws, size_t ws_size,
                              hipStream_t stream) {
  const float* nb = (const float*)d_in[0];
  const int* zn = (const int*)d_in[1];
  const float* dist = (const float*)d_in[2];
  const int* ei = (const int*)d_in[3];
  const float* wig = (const float*)d_in[4];
  const float* aemb = (const float*)d_in[5];
  const float* W_rbf = (const float*)d_in[6];
  const float* W_gate = (const float*)d_in[7];
  const float* W_msg = (const float*)d_in[8];
  const float* alpha = (const float*)d_in[9];
  const float* W_val = (const float*)d_in[10];
  const float* W_out = (const float*)d_in[11];
  float* out = (float*)d_out;

  // workspace layout (~107 MB)
  char* p = (char*)d_ws;
  float* Q = (float*)p;                   p += 1024 * 4;
  unsigned int* m_enc = (unsigned int*)p; p += (size_t)NN * 8 * 4;
  float* den = (float*)p;                 p += (size_t)NN * 8 * 4;
  float* logits = (float*)p;              p += (size_t)NE * 8 * 4;
  __hip_bfloat16* gate_ws = (__hip_bfloat16*)p; p += (size_t)NE * 128 * 2;
  short* Wp1h = (short*)p; p += 8192 * 2;
  short* Wp1l = (short*)p; p += 8192 * 2;
  short* Wp2h = (short*)p; p += 8192 * 2;
  short* Wp2l = (short*)p; p += 8192 * 2;
  short* Wp3h = (short*)p; p += 16384 * 2;
  short* Wp3l = (short*)p; p += 16384 * 2;
  short* Wp4h = (short*)p; p += 16384 * 2;
  short* Wp4l = (short*)p; p += 16384 * 2;
  short* Gb = (short*)p;                  p += (size_t)NE * 384 * 2;

  hipMemsetAsync(d_out, 0, (size_t)NN * 3 * 4, stream);
  hipMemsetAsync(m_enc, 0, (size_t)NN * 8 * 4, stream);
  hipMemsetAsync(den, 0, (size_t)NN * 8 * 4, stream);

  prep_kernel<<<192, 256, 0, stream>>>(W_msg, W_val, W_out, W_rbf, W_gate, Q,
                                       Wp1h, Wp1l, Wp2h, Wp2l, Wp3h, Wp3l, Wp4h, Wp4l);
  pass1_kernel<<<(NE + 63) / 64, 256, 0, stream>>>(nb, zn, dist, ei, wig, aemb, alpha,
                                                   Wp1h, Wp1l, Wp2h, Wp2l, Wp3h, Wp3l,
                                                   logits, m_enc, gate_ws, Gb);
  pass2_kernel<<<(NE * 8 + 255) / 256, 256, 0, stream>>>(logits, ei, m_enc, den);
  pass3_kernel<<<(NE + 63) / 64, 256, 0, stream>>>(ei, logits, m_enc, den,
                                                   gate_ws, Q, Wp4h, Wp4l, Gb, out);
}